// Round 13
// baseline (123.192 us; speedup 1.0000x reference)
//
#include <hip/hip_runtime.h>

#define NN 10000
#define NE 640000
#define NB 313          // buckets of 32 nodes; also # partition blocks
#define RSTRIDE 2688    // slots per bucket (mean 2045, sigma~45)
#define EPB 2048        // edges per partition block
#define G1B 1250        // gemm1 blocks (8 rows each)

__device__ __forceinline__ unsigned short f2bf(float x) {   // RNE
    unsigned u = __float_as_uint(x);
    u += 0x7FFFu + ((u >> 16) & 1u);
    return (unsigned short)(u >> 16);
}
__device__ __forceinline__ float bflo(unsigned u) { return __uint_as_float(u << 16); }
__device__ __forceinline__ float bfhi(unsigned u) { return __uint_as_float(u & 0xFFFF0000u); }

__device__ __forceinline__ void acc8p(float* acc, uint4 u) {
    acc[0] += bflo(u.x); acc[1] += bfhi(u.x);
    acc[2] += bflo(u.y); acc[3] += bfhi(u.y);
    acc[4] += bflo(u.z); acc[5] += bfhi(u.z);
    acc[6] += bflo(u.w); acc[7] += bfhi(u.w);
}
__device__ __forceinline__ void acc4p(float* acc, uint2 u) {
    acc[0] += bflo(u.x); acc[1] += bfhi(u.x);
    acc[2] += bflo(u.y); acc[3] += bfhi(u.y);
}

struct SMpart { int hist[NB]; int scanv[NB + 1]; int gbase[NB]; int lcur[NB];
                unsigned stage[EPB]; };
struct SMbuild { int sbase[NB + 1]; int hist32[32]; int cur32[32]; float isqs[32];
                 unsigned stage[RSTRIDE]; };
union SMu {
    SMpart p;
    SMbuild b;
    float xs[16][128];
};

__global__ void zero_kernel(int* __restrict__ cur) {
    if (threadIdx.x < NB) cur[threadIdx.x] = 0;
}

// ---- gemm1: 8 rows of Y = X[f32] @ W[128x128] -> bf16 (unscaled) ----
__device__ __forceinline__ void gemm1_block(const float* __restrict__ X,
                                            const float* __restrict__ W,
                                            unsigned short* __restrict__ Y,
                                            float (*xs)[128], int vb, int tid) {
    int row0 = vb * 8;
    for (int idx = tid; idx < 8 * 128; idx += 256) {
        int r = idx >> 7, k = idx & 127;
        xs[r][k] = X[(size_t)(row0 + r) * 128 + k];
    }
    __syncthreads();
    int ct = tid & 31, r = tid >> 5, c = ct * 4;
    float4 acc = make_float4(0.f, 0.f, 0.f, 0.f);
    #pragma unroll 8
    for (int k = 0; k < 128; ++k) {
        float xv = xs[r][k];
        float4 w = *reinterpret_cast<const float4*>(W + (size_t)k * 128 + c);
        acc.x += xv * w.x; acc.y += xv * w.y; acc.z += xv * w.z; acc.w += xv * w.w;
    }
    ushort4 o;
    o.x = f2bf(acc.x); o.y = f2bf(acc.y); o.z = f2bf(acc.z); o.w = f2bf(acc.w);
    *reinterpret_cast<ushort4*>(Y + (size_t)(row0 + r) * 128 + c) = o;
}

// ---- bf16-in GEMM; per-row isq prescale in f32 epilogue ----
template<int NOUTc, int ROWS>
__device__ __forceinline__ void gemm_bf_block(const unsigned short* __restrict__ Xb,
                                              const float* __restrict__ W,
                                              const float* __restrict__ isqv,
                                              unsigned short* __restrict__ Y,
                                              float (*xs)[128], int vb, int tid) {
    int row0 = vb * ROWS;
    const unsigned* Xu = reinterpret_cast<const unsigned*>(Xb + (size_t)row0 * 128);
    for (int idx = tid; idx < ROWS * 64; idx += 256) {
        unsigned u = Xu[idx];
        int r = idx >> 6, kk = idx & 63;
        xs[r][kk * 2]     = bflo(u);
        xs[r][kk * 2 + 1] = bfhi(u);
    }
    __syncthreads();
    constexpr int COLT = NOUTc / 4;
    int ct = tid % COLT, r = tid / COLT, c = ct * 4;
    float4 acc = make_float4(0.f, 0.f, 0.f, 0.f);
    #pragma unroll 8
    for (int k = 0; k < 128; ++k) {
        float xv = xs[r][k];
        float4 w = *reinterpret_cast<const float4*>(W + (size_t)k * NOUTc + c);
        acc.x += xv * w.x; acc.y += xv * w.y; acc.z += xv * w.z; acc.w += xv * w.w;
    }
    int gr = row0 + r;
    float sc = isqv[gr];
    acc.x *= sc; acc.y *= sc; acc.z *= sc; acc.w *= sc;
    ushort4 o;
    o.x = f2bf(acc.x); o.y = f2bf(acc.y); o.z = f2bf(acc.z); o.w = f2bf(acc.w);
    *reinterpret_cast<ushort4*>(Y + (size_t)gr * NOUTc + c) = o;
}

// ---- partition: one block of EPB edges -> bucketed records ----
__device__ __forceinline__ void partition_block(const int* __restrict__ src,
                                                const int* __restrict__ dst,
                                                int* __restrict__ bcur,
                                                unsigned* __restrict__ edge_part,
                                                SMpart& p, int bid, int tid) {
    for (int i = tid; i < NB; i += 256) p.hist[i] = 0;
    __syncthreads();
    int gi = bid * EPB + tid * 8;
    unsigned rec[8];
    bool act = gi < NE;
    if (act) {
        int4 s0 = *reinterpret_cast<const int4*>(src + gi);
        int4 s1 = *reinterpret_cast<const int4*>(src + gi + 4);
        int4 d0 = *reinterpret_cast<const int4*>(dst + gi);
        int4 d1 = *reinterpret_cast<const int4*>(dst + gi + 4);
        rec[0] = ((unsigned)d0.x << 14) | (unsigned)s0.x;
        rec[1] = ((unsigned)d0.y << 14) | (unsigned)s0.y;
        rec[2] = ((unsigned)d0.z << 14) | (unsigned)s0.z;
        rec[3] = ((unsigned)d0.w << 14) | (unsigned)s0.w;
        rec[4] = ((unsigned)d1.x << 14) | (unsigned)s1.x;
        rec[5] = ((unsigned)d1.y << 14) | (unsigned)s1.y;
        rec[6] = ((unsigned)d1.z << 14) | (unsigned)s1.z;
        rec[7] = ((unsigned)d1.w << 14) | (unsigned)s1.w;
        #pragma unroll
        for (int k = 0; k < 8; ++k) atomicAdd(&p.hist[rec[k] >> 19], 1);
    }
    __syncthreads();
    if (tid < 64) {          // wave-0 exclusive scan of hist
        int carry = 0;
        for (int c = 0; c < NB; c += 64) {
            int idx = c + tid;
            int v = (idx < NB) ? p.hist[idx] : 0;
            int incl = v;
            #pragma unroll
            for (int d = 1; d < 64; d <<= 1) {
                int t = __shfl_up(incl, d, 64);
                if (tid >= d) incl += t;
            }
            if (idx < NB) p.scanv[idx] = carry + incl - v;
            carry += __shfl(incl, 63, 64);
        }
        if (tid == 0) p.scanv[NB] = carry;
    }
    __syncthreads();
    for (int bb = tid; bb < NB; bb += 256) {
        p.gbase[bb] = atomicAdd(&bcur[bb], p.hist[bb]);
        p.lcur[bb]  = p.scanv[bb];
    }
    __syncthreads();
    if (act) {
        #pragma unroll
        for (int k = 0; k < 8; ++k) {
            int bb = rec[k] >> 19;
            int pp = atomicAdd(&p.lcur[bb], 1);
            p.stage[pp] = rec[k];
        }
    }
    __syncthreads();
    int tot = p.scanv[NB];
    for (int i = tid; i < tot; i += 256) {
        unsigned r = p.stage[i];
        int bb = r >> 19;
        edge_part[bb * RSTRIDE + p.gbase[bb] + (i - p.scanv[bb])] = r;
    }
}

// ---- build: one bucket -> offs/inv_sqrt + node-sorted CSR (ushort src)
//      + in-place scale of T1 rows by inv_sqrt (prepares PS aggregation) ----
__device__ __forceinline__ void build_block(const unsigned* __restrict__ edge_part,
                                            const int* __restrict__ bcur,
                                            int* __restrict__ offs,
                                            float* __restrict__ inv_sqrt,
                                            unsigned short* __restrict__ edge_src,
                                            unsigned* __restrict__ T1u,
                                            SMbuild& b, int bid, int tid) {
    if (tid < 64) {
        int carry = 0;
        for (int c = 0; c < NB; c += 64) {
            int idx = c + tid;
            int v = (idx < NB) ? bcur[idx] : 0;
            int incl = v;
            #pragma unroll
            for (int d = 1; d < 64; d <<= 1) {
                int t = __shfl_up(incl, d, 64);
                if (tid >= d) incl += t;
            }
            if (idx < NB) b.sbase[idx] = carry + incl - v;
            carry += __shfl(incl, 63, 64);
        }
    }
    if (tid < 32) b.hist32[tid] = 0;
    __syncthreads();
    int cnt = bcur[bid];
    int base = b.sbase[bid];
    const unsigned* part = edge_part + (size_t)bid * RSTRIDE;
    for (int k = tid; k < cnt; k += 256)
        atomicAdd(&b.hist32[(part[k] >> 14) & 31], 1);
    __syncthreads();
    if (tid < 32) {
        int v = b.hist32[tid];
        int incl = v;
        #pragma unroll
        for (int d = 1; d < 32; d <<= 1) {
            int t = __shfl_up(incl, d, 32);
            if (tid >= d) incl += t;
        }
        int excl = incl - v;
        b.cur32[tid] = excl;
        float isq = rsqrtf((float)(v + 1));
        b.isqs[tid] = isq;
        int node = bid * 32 + tid;
        if (node < NN) {
            offs[node] = base + excl;
            inv_sqrt[node] = isq;
        }
        if (bid == NB - 1 && tid == 0) offs[NN] = base + cnt;
    }
    __syncthreads();
    for (int k = tid; k < cnt; k += 256) {
        unsigned r = part[k];
        int pp = atomicAdd(&b.cur32[(r >> 14) & 31], 1);
        b.stage[pp] = r & 0x3FFFu;
    }
    __syncthreads();
    for (int k = tid; k < cnt; k += 256)
        edge_src[base + k] = (unsigned short)b.stage[k];
    // scale T1 rows of this bucket's nodes in place: T1[node] *= isq_node
    int nvalid = NN - bid * 32;
    if (nvalid > 32) nvalid = 32;
    for (int idx = tid; idx < nvalid * 64; idx += 256) {
        int nl = idx >> 6, k = idx & 63;
        float sc = b.isqs[nl];
        size_t off = (size_t)(bid * 32 + nl) * 64 + k;
        unsigned u = T1u[off];
        T1u[off] = (unsigned)f2bf(bflo(u) * sc) | ((unsigned)f2bf(bfhi(u) * sc) << 16);
    }
}

// ======================= kernels =======================
__global__ __launch_bounds__(256) void part_gemm1_kernel(
        const int* __restrict__ src, const int* __restrict__ dst,
        int* __restrict__ bcur, unsigned* __restrict__ edge_part,
        const float* __restrict__ X, const float* __restrict__ W,
        unsigned short* __restrict__ Y) {
    __shared__ SMu sm;
    int tid = threadIdx.x;
    if (blockIdx.x >= NB) {
        gemm1_block(X, W, Y, sm.xs, blockIdx.x - NB, tid);
        return;
    }
    partition_block(src, dst, bcur, edge_part, sm.p, blockIdx.x, tid);
}

__global__ __launch_bounds__(256) void build_kernel(
        const unsigned* __restrict__ edge_part, const int* __restrict__ bcur,
        int* __restrict__ offs, float* __restrict__ inv_sqrt,
        unsigned short* __restrict__ edge_src, unsigned* __restrict__ T1u) {
    __shared__ SMu sm;
    build_block(edge_part, bcur, offs, inv_sqrt, edge_src, T1u, sm.b,
                blockIdx.x, threadIdx.x);
}

// 128-ch aggregation over pre-scaled rows. 2 waves/node (split chains);
// 4 groups of 16 lanes per wave, one edge per group (uint4 = 8 ch/lane);
// 32-edge unroll = 8 row-gathers in flight per lane.
__global__ __launch_bounds__(128) void agg128_kernel(
        const unsigned short* __restrict__ H, const unsigned short* __restrict__ esrc,
        const int* __restrict__ offs, const float* __restrict__ isqv,
        const float* __restrict__ bias, uint4* __restrict__ Aout) {
    __shared__ float red[16][9];
    int node = blockIdx.x;
    int tid = threadIdx.x, lane = tid & 63, wv = tid >> 6;
    int l = lane & 15, g = lane >> 4;
    int s = offs[node], e = offs[node + 1];
    int deg = e - s;
    int half = ((deg >> 1) + 3) & ~3;
    int js = s + wv * half;
    if (js > e) js = e;
    int mid = s + half;
    int je = wv ? e : (mid < e ? mid : e);
    int colb = l * 8;
    float acc[8];
    #pragma unroll
    for (int i = 0; i < 8; ++i) acc[i] = 0.f;
    int j = js;
    for (; j + 32 <= je; j += 32) {
        int s0 = esrc[j + g],      s1 = esrc[j + 4 + g];
        int s2 = esrc[j + 8 + g],  s3 = esrc[j + 12 + g];
        int s4 = esrc[j + 16 + g], s5 = esrc[j + 20 + g];
        int s6 = esrc[j + 24 + g], s7 = esrc[j + 28 + g];
        uint4 a0 = *reinterpret_cast<const uint4*>(H + (size_t)s0 * 128 + colb);
        uint4 a1 = *reinterpret_cast<const uint4*>(H + (size_t)s1 * 128 + colb);
        uint4 a2 = *reinterpret_cast<const uint4*>(H + (size_t)s2 * 128 + colb);
        uint4 a3 = *reinterpret_cast<const uint4*>(H + (size_t)s3 * 128 + colb);
        uint4 a4 = *reinterpret_cast<const uint4*>(H + (size_t)s4 * 128 + colb);
        uint4 a5 = *reinterpret_cast<const uint4*>(H + (size_t)s5 * 128 + colb);
        uint4 a6 = *reinterpret_cast<const uint4*>(H + (size_t)s6 * 128 + colb);
        uint4 a7 = *reinterpret_cast<const uint4*>(H + (size_t)s7 * 128 + colb);
        acc8p(acc, a0); acc8p(acc, a1); acc8p(acc, a2); acc8p(acc, a3);
        acc8p(acc, a4); acc8p(acc, a5); acc8p(acc, a6); acc8p(acc, a7);
    }
    for (; j + 16 <= je; j += 16) {
        int s0 = esrc[j + g],     s1 = esrc[j + 4 + g];
        int s2 = esrc[j + 8 + g], s3 = esrc[j + 12 + g];
        uint4 a0 = *reinterpret_cast<const uint4*>(H + (size_t)s0 * 128 + colb);
        uint4 a1 = *reinterpret_cast<const uint4*>(H + (size_t)s1 * 128 + colb);
        uint4 a2 = *reinterpret_cast<const uint4*>(H + (size_t)s2 * 128 + colb);
        uint4 a3 = *reinterpret_cast<const uint4*>(H + (size_t)s3 * 128 + colb);
        acc8p(acc, a0); acc8p(acc, a1); acc8p(acc, a2); acc8p(acc, a3);
    }
    for (; j + 4 <= je; j += 4) {
        int s0 = esrc[j + g];
        uint4 a0 = *reinterpret_cast<const uint4*>(H + (size_t)s0 * 128 + colb);
        acc8p(acc, a0);
    }
    int rem = je - j;
    if (g < rem) {
        int s0 = esrc[j + g];
        uint4 a0 = *reinterpret_cast<const uint4*>(H + (size_t)s0 * 128 + colb);
        acc8p(acc, a0);
    }
    #pragma unroll
    for (int i = 0; i < 8; ++i) {
        acc[i] += __shfl_down(acc[i], 32);
        acc[i] += __shfl_down(acc[i], 16);
    }
    if (wv == 1 && lane < 16) {
        #pragma unroll
        for (int i = 0; i < 8; ++i) red[l][i] = acc[i];
    }
    __syncthreads();
    if (wv == 0 && lane < 16) {
        float isq = isqv[node];
        uint4 uv = *reinterpret_cast<const uint4*>(H + (size_t)node * 128 + colb);
        float sv[8] = { bflo(uv.x), bfhi(uv.x), bflo(uv.y), bfhi(uv.y),
                        bflo(uv.z), bfhi(uv.z), bflo(uv.w), bfhi(uv.w) };
        float o[8];
        #pragma unroll
        for (int i = 0; i < 8; ++i)
            o[i] = fmaxf(isq * (acc[i] + red[l][i] + sv[i]) + bias[colb + i], 0.f);
        uint4 ov;
        ov.x = (unsigned)f2bf(o[0]) | ((unsigned)f2bf(o[1]) << 16);
        ov.y = (unsigned)f2bf(o[2]) | ((unsigned)f2bf(o[3]) << 16);
        ov.z = (unsigned)f2bf(o[4]) | ((unsigned)f2bf(o[5]) << 16);
        ov.w = (unsigned)f2bf(o[6]) | ((unsigned)f2bf(o[7]) << 16);
        Aout[(size_t)node * 16 + l] = ov;
    }
}

// 64-ch final aggregation (pre-scaled rows), f32 out, no relu
__global__ __launch_bounds__(128) void agg64_kernel(
        const unsigned short* __restrict__ H, const unsigned short* __restrict__ esrc,
        const int* __restrict__ offs, const float* __restrict__ isqv,
        const float* __restrict__ bias, float* __restrict__ out) {
    __shared__ float red[16][5];
    int node = blockIdx.x;
    int tid = threadIdx.x, lane = tid & 63, wv = tid >> 6;
    int l = lane & 15, g = lane >> 4;
    int s = offs[node], e = offs[node + 1];
    int deg = e - s;
    int half = ((deg >> 1) + 3) & ~3;
    int js = s + wv * half;
    if (js > e) js = e;
    int mid = s + half;
    int je = wv ? e : (mid < e ? mid : e);
    int colb = l * 4;
    float acc[4] = {0.f, 0.f, 0.f, 0.f};
    int j = js;
    for (; j + 32 <= je; j += 32) {
        int s0 = esrc[j + g],      s1 = esrc[j + 4 + g];
        int s2 = esrc[j + 8 + g],  s3 = esrc[j + 12 + g];
        int s4 = esrc[j + 16 + g], s5 = esrc[j + 20 + g];
        int s6 = esrc[j + 24 + g], s7 = esrc[j + 28 + g];
        uint2 a0 = *reinterpret_cast<const uint2*>(H + (size_t)s0 * 64 + colb);
        uint2 a1 = *reinterpret_cast<const uint2*>(H + (size_t)s1 * 64 + colb);
        uint2 a2 = *reinterpret_cast<const uint2*>(H + (size_t)s2 * 64 + colb);
        uint2 a3 = *reinterpret_cast<const uint2*>(H + (size_t)s3 * 64 + colb);
        uint2 a4 = *reinterpret_cast<const uint2*>(H + (size_t)s4 * 64 + colb);
        uint2 a5 = *reinterpret_cast<const uint2*>(H + (size_t)s5 * 64 + colb);
        uint2 a6 = *reinterpret_cast<const uint2*>(H + (size_t)s6 * 64 + colb);
        uint2 a7 = *reinterpret_cast<const uint2*>(H + (size_t)s7 * 64 + colb);
        acc4p(acc, a0); acc4p(acc, a1); acc4p(acc, a2); acc4p(acc, a3);
        acc4p(acc, a4); acc4p(acc, a5); acc4p(acc, a6); acc4p(acc, a7);
    }
    for (; j + 16 <= je; j += 16) {
        int s0 = esrc[j + g],     s1 = esrc[j + 4 + g];
        int s2 = esrc[j + 8 + g], s3 = esrc[j + 12 + g];
        uint2 a0 = *reinterpret_cast<const uint2*>(H + (size_t)s0 * 64 + colb);
        uint2 a1 = *reinterpret_cast<const uint2*>(H + (size_t)s1 * 64 + colb);
        uint2 a2 = *reinterpret_cast<const uint2*>(H + (size_t)s2 * 64 + colb);
        uint2 a3 = *reinterpret_cast<const uint2*>(H + (size_t)s3 * 64 + colb);
        acc4p(acc, a0); acc4p(acc, a1); acc4p(acc, a2); acc4p(acc, a3);
    }
    for (; j + 4 <= je; j += 4) {
        int s0 = esrc[j + g];
        uint2 a0 = *reinterpret_cast<const uint2*>(H + (size_t)s0 * 64 + colb);
        acc4p(acc, a0);
    }
    int rem = je - j;
    if (g < rem) {
        int s0 = esrc[j + g];
        uint2 a0 = *reinterpret_cast<const uint2*>(H + (size_t)s0 * 64 + colb);
        acc4p(acc, a0);
    }
    #pragma unroll
    for (int i = 0; i < 4; ++i) {
        acc[i] += __shfl_down(acc[i], 32);
        acc[i] += __shfl_down(acc[i], 16);
    }
    if (wv == 1 && lane < 16) {
        #pragma unroll
        for (int i = 0; i < 4; ++i) red[l][i] = acc[i];
    }
    __syncthreads();
    if (wv == 0 && lane < 16) {
        float isq = isqv[node];
        uint2 uv = *reinterpret_cast<const uint2*>(H + (size_t)node * 64 + colb);
        float sv[4] = { bflo(uv.x), bfhi(uv.x), bflo(uv.y), bfhi(uv.y) };
        float4 ov;
        ov.x = isq * (acc[0] + red[l][0] + sv[0]) + bias[colb];
        ov.y = isq * (acc[1] + red[l][1] + sv[1]) + bias[colb + 1];
        ov.z = isq * (acc[2] + red[l][2] + sv[2]) + bias[colb + 2];
        ov.w = isq * (acc[3] + red[l][3] + sv[3]) + bias[colb + 3];
        *reinterpret_cast<float4*>(out + (size_t)node * 64 + colb) = ov;
    }
}

template<int N>
__global__ __launch_bounds__(256) void gemm_bf_kernel(
        const unsigned short* __restrict__ X, const float* __restrict__ W,
        const float* __restrict__ isqv, unsigned short* __restrict__ Y) {
    __shared__ SMu sm;
    gemm_bf_block<N, 256 / (N / 4)>(X, W, isqv, Y, sm.xs, blockIdx.x, threadIdx.x);
}

extern "C" void kernel_launch(void* const* d_in, const int* in_sizes, int n_in,
                              void* d_out, int out_size, void* d_ws, size_t ws_size,
                              hipStream_t stream) {
    const float* x  = (const float*)d_in[0];
    const int*   ei = (const int*)d_in[1];
    const float* W1 = (const float*)d_in[2];
    const float* b1 = (const float*)d_in[3];
    const float* W2 = (const float*)d_in[4];
    const float* b2 = (const float*)d_in[5];
    const float* W3 = (const float*)d_in[6];
    const float* b3 = (const float*)d_in[7];
    float* out = (float*)d_out;

    const int* src = ei;
    const int* dst = ei + NE;

    char* ws = (char*)d_ws;
    int*            bcur      = (int*)(ws);                        // 1,252 B
    float*          inv_sqrt  = (float*)(ws + 4096);               // 40,000 B
    int*            offs      = (int*)(ws + 45056);                // 40,004 B
    unsigned*       edge_part = (unsigned*)(ws + 86016);           // 3,365,376 B
    unsigned short* edge_src  = (unsigned short*)(ws + 3451392);   // 1,280,000 B
    unsigned short* T1        = (unsigned short*)(ws + 6011392);   // 2,560,000 B
    unsigned short* A         = (unsigned short*)(ws + 8571392);   // 2,560,000 B
    unsigned short* T2        = (unsigned short*)edge_part;        // alias (dead after build)
    unsigned short* T3        = T1;                                // alias (dead after agg1)

    zero_kernel<<<1, 320, 0, stream>>>(bcur);
    part_gemm1_kernel<<<NB + G1B, 256, 0, stream>>>(src, dst, bcur, edge_part,
                                                    x, W1, T1);
    build_kernel<<<NB, 256, 0, stream>>>(edge_part, bcur, offs, inv_sqrt, edge_src,
                                         (unsigned*)T1);
    agg128_kernel<<<NN, 128, 0, stream>>>(T1, edge_src, offs, inv_sqrt, b1,
                                          (uint4*)A);
    gemm_bf_kernel<128><<<NN / 8, 256, 0, stream>>>(A, W2, inv_sqrt, T2);
    agg128_kernel<<<NN, 128, 0, stream>>>(T2, edge_src, offs, inv_sqrt, b2,
                                          (uint4*)A);
    gemm_bf_kernel<64><<<NN / 16, 256, 0, stream>>>(A, W3, inv_sqrt, T3);
    agg64_kernel<<<NN, 128, 0, stream>>>(T3, edge_src, offs, inv_sqrt, b3, out);
}